// Round 6
// baseline (247.113 us; speedup 1.0000x reference)
//
#include <hip/hip_runtime.h>
#include <hip/hip_bf16.h>

#define NN      150000
#define NUSERS  50000
#define DD      128
#define EE      500000
#define BB      16384
#define NBLK    586          // ceil(NN/256)

using short8  = __attribute__((ext_vector_type(8))) short;
using ushort8 = __attribute__((ext_vector_type(8))) unsigned short;
using f32x4   = __attribute__((ext_vector_type(4))) float;

__device__ __forceinline__ short f2bf(float v) {
    __hip_bfloat16 b = __float2bfloat16(v);      // RNE; pairs fuse to v_cvt_pk_bf16_f32
    return __builtin_bit_cast(short, b);
}
__device__ __forceinline__ float bf2f(unsigned short b) {
    return __uint_as_float(((unsigned)b) << 16);
}

// ---------------- degree count (int) ----------------
__global__ __launch_bounds__(256) void count_k(const int* __restrict__ dst,
                                               int* __restrict__ cnt) {
    int e = blockIdx.x * 256 + threadIdx.x;
    if (e < EE) atomicAdd(&cnt[dst[e]], 1);
}

// ---------------- hierarchical exclusive scan of cnt -> rowptr ----------------
__global__ __launch_bounds__(256) void scan1_k(const int* __restrict__ cnt,
                                               int* __restrict__ rowptr,
                                               int* __restrict__ bsum) {
    __shared__ int s[256];
    int t = threadIdx.x;
    int i = blockIdx.x * 256 + t;
    int v = (i < NN) ? cnt[i] : 0;
    s[t] = v; __syncthreads();
    for (int off = 1; off < 256; off <<= 1) {
        int x = (t >= off) ? s[t - off] : 0;
        __syncthreads();
        s[t] += x;
        __syncthreads();
    }
    if (i < NN) rowptr[i] = s[t] - v;           // block-local exclusive
    if (t == 255) bsum[blockIdx.x] = s[255];
}

__global__ __launch_bounds__(1024) void scan2_k(int* __restrict__ bsum) {
    __shared__ int s[1024];
    int t = threadIdx.x;
    int v = (t < NBLK) ? bsum[t] : 0;
    s[t] = v; __syncthreads();
    for (int off = 1; off < 1024; off <<= 1) {
        int x = (t >= off) ? s[t - off] : 0;
        __syncthreads();
        s[t] += x;
        __syncthreads();
    }
    if (t < NBLK) bsum[t] = s[t] - v;           // exclusive block offsets
}

// scan3 + dis fused
__global__ __launch_bounds__(256) void scan3_k(int* __restrict__ rowptr,
                                               const int* __restrict__ bsum,
                                               int* __restrict__ cur,
                                               const int* __restrict__ cnt,
                                               float* __restrict__ dis) {
    int i = blockIdx.x * 256 + threadIdx.x;
    if (i < NN) {
        int v = rowptr[i] + bsum[blockIdx.x];
        rowptr[i] = v;
        cur[i] = v;
        dis[i] = rsqrtf((float)cnt[i] + 1.0f);
    }
    if (i == 0) rowptr[NN] = EE;
}

// ---------------- CSR fill (counting sort by dst), packed (src, dis[src]) ----
__global__ __launch_bounds__(256) void fill_k(const int* __restrict__ src,
                                              const int* __restrict__ dst,
                                              const float* __restrict__ dis,
                                              int* __restrict__ cur,
                                              int2* __restrict__ sedge) {
    int e = blockIdx.x * 256 + threadIdx.x;
    if (e < EE) {
        int d = dst[e], s = src[e];
        int pos = atomicAdd(&cur[d], 1);
        sedge[pos] = make_int2(s, __float_as_int(dis[s]));
    }
}

// ---------------- Wfrag prep: per-lane MFMA fragments, bf16 ----------------
// F[((ct*4 + kk)*64 + lane)*8 + e] = W[kk*32 + (lane>>4)*8 + e][ct*16 + (lane&15)]
// Same layout serves as MFMA *A-operand* in the swapped scheme (layout symmetry).
__global__ __launch_bounds__(256) void wfrag_k(const float* __restrict__ W1,
                                               const float* __restrict__ W2,
                                               short* __restrict__ F1,
                                               short* __restrict__ F2) {
    int idx = blockIdx.x * 256 + threadIdx.x;   // [0, 32768)
    int m = idx >> 14;
    int i = idx & 16383;
    int e  = i & 7;
    int l  = (i >> 3) & 63;
    int kk = (i >> 9) & 3;
    int ct = i >> 11;
    int k = kk * 32 + (l >> 4) * 8 + e;
    int c = ct * 16 + (l & 15);
    const float* W = m ? W2 : W1;
    short*       F = m ? F2 : F1;
    F[i] = f2bf(W[k * DD + c]);
}

// ---------------- MFMA GEMM (swapped operands): hout(bf16) = A @ W ----------
// MODE 0: A = concat(A0[0:nsplit], A1) fp32, raw.            Layer 1.
// MODE 1: A = relu(bf16(Ab) * coefs[c] + coefs[128+c]).      Layer 2.
// mfma(D = Wfrag x rowfrag): D[m][n] = h[row = n][col = ct*16 + m].
// Lane holds row = r0+(lane&15) fixed, cols ct*16 + (lane>>4)*4 + j (j=0..3
// consecutive) -> 8B packed stores. A-row loads are nontemporal so the
// streamed data doesn't evict Wfrag from L1.
template<int MODE>
__global__ __launch_bounds__(256) void gemm_mfma_k(const float* __restrict__ A0,
                                                   const float* __restrict__ A1,
                                                   int nsplit,
                                                   const unsigned short* __restrict__ Ab,
                                                   const float* __restrict__ coefs,
                                                   const short* __restrict__ Wfrag,
                                                   unsigned short* __restrict__ hout) {
    int wave = threadIdx.x >> 6;
    int lane = threadIdx.x & 63;
    int r0 = blockIdx.x * 64 + wave * 16;

    int row = r0 + (lane & 15);
    int lr = row > NN - 1 ? NN - 1 : row;       // clamped load row
    const float* arow = nullptr;
    const unsigned short* brow = nullptr;
    if (MODE == 0) arow = (lr < nsplit) ? A0 + (size_t)lr * DD
                                        : A1 + (size_t)(lr - nsplit) * DD;
    else           brow = Ab + (size_t)lr * DD;

    int kgrp = lane >> 4;   // 0..3

    f32x4 acc[8];
#pragma unroll
    for (int ct = 0; ct < 8; ++ct) acc[ct] = (f32x4){0.f, 0.f, 0.f, 0.f};

#pragma unroll
    for (int kk = 0; kk < 4; ++kk) {
        int d0 = kk * 32 + kgrp * 8;
        float v[8];
        if (MODE == 0) {
            f32x4 va = __builtin_nontemporal_load((const f32x4*)(arow + d0));
            f32x4 vb = __builtin_nontemporal_load((const f32x4*)(arow + d0 + 4));
#pragma unroll
            for (int j = 0; j < 4; ++j) { v[j] = va[j]; v[4 + j] = vb[j]; }
        } else {
            ushort8 u = __builtin_nontemporal_load((const ushort8*)(brow + d0));
            f32x4 s1 = *(const f32x4*)(coefs + d0);
            f32x4 s2 = *(const f32x4*)(coefs + d0 + 4);
            f32x4 t1 = *(const f32x4*)(coefs + 128 + d0);
            f32x4 t2 = *(const f32x4*)(coefs + 128 + d0 + 4);
#pragma unroll
            for (int j = 0; j < 4; ++j) {
                v[j]     = fmaxf(bf2f(u[j])     * s1[j] + t1[j], 0.f);
                v[4 + j] = fmaxf(bf2f(u[4 + j]) * s2[j] + t2[j], 0.f);
            }
        }
        short8 rfrag;
#pragma unroll
        for (int j = 0; j < 8; ++j) rfrag[j] = f2bf(v[j]);

        const short8* wf = (const short8*)Wfrag;
#pragma unroll
        for (int ct = 0; ct < 8; ++ct) {
            short8 wfr = wf[(ct * 4 + kk) * 64 + lane];
            // swapped: Wfrag is the A-operand, row data is the B-operand
            acc[ct] = __builtin_amdgcn_mfma_f32_16x16x32_bf16(wfr, rfrag, acc[ct], 0, 0, 0);
        }
    }

    if (row < NN) {
        size_t rb = (size_t)row * DD;
#pragma unroll
        for (int ct = 0; ct < 8; ++ct) {
            int col = ct * 16 + kgrp * 4;
            unsigned p0 = (unsigned)(unsigned short)f2bf(acc[ct][0])
                        | ((unsigned)(unsigned short)f2bf(acc[ct][1]) << 16);
            unsigned p1 = (unsigned)(unsigned short)f2bf(acc[ct][2])
                        | ((unsigned)(unsigned short)f2bf(acc[ct][3]) << 16);
            uint2 p; p.x = p0; p.y = p1;
            *(uint2*)(hout + rb + col) = p;
        }
    }
}

// ---------------- CSR gather: 4 rows per wave (16-lane groups, ushort8) -----
// aggb[i] = bf16( dis[i]*sum(dis[s]*h[s]) + dis[i]^2*h[i] )
__global__ __launch_bounds__(256) void gather_k(const unsigned short* __restrict__ h,
                                                const int2* __restrict__ se,
                                                const int* __restrict__ rowptr,
                                                const float* __restrict__ dis,
                                                unsigned short* __restrict__ aggb) {
    int t = threadIdx.x;
    int l = t & 15;                       // lane within row-group (8 cols each)
    int row = blockIdx.x * 16 + (t >> 4); // 16 rows per block (4 per wave)
    if (row >= NN) return;
    int p0 = rowptr[row], p1 = rowptr[row + 1];
    const ushort8* hp = (const ushort8*)h;

    float acc[8];
#pragma unroll
    for (int j = 0; j < 8; ++j) acc[j] = 0.f;

    for (int base = p0; base < p1; base += 4) {
        int i1 = min(base + 1, p1 - 1);
        int i2 = min(base + 2, p1 - 1);
        int i3 = min(base + 3, p1 - 1);
        int2 e0 = se[base], e1 = se[i1], e2 = se[i2], e3 = se[i3];
        ushort8 h0 = hp[(size_t)e0.x * 16 + l];
        ushort8 h1 = hp[(size_t)e1.x * 16 + l];
        ushort8 h2 = hp[(size_t)e2.x * 16 + l];
        ushort8 h3 = hp[(size_t)e3.x * 16 + l];
        float w0 = __int_as_float(e0.y);
        float w1 = (base + 1 < p1) ? __int_as_float(e1.y) : 0.f;
        float w2 = (base + 2 < p1) ? __int_as_float(e2.y) : 0.f;
        float w3 = (base + 3 < p1) ? __int_as_float(e3.y) : 0.f;
#pragma unroll
        for (int j = 0; j < 8; ++j) {
            acc[j] += w0 * bf2f(h0[j]) + w1 * bf2f(h1[j])
                    + w2 * bf2f(h2[j]) + w3 * bf2f(h3[j]);
        }
    }
    float d  = dis[row];
    float d2 = d * d;
    ushort8 hs = hp[(size_t)row * 16 + l];
    ushort8 o;
#pragma unroll
    for (int j = 0; j < 8; ++j)
        o[j] = (unsigned short)f2bf(d * acc[j] + d2 * bf2f(hs[j]));
    ((ushort8*)aggb)[(size_t)row * 16 + l] = o;
}

// ---------------- BN stats on bf16 x: per-column sum & sumsq ----------------
__global__ __launch_bounds__(256) void bnstats_k(const unsigned short* __restrict__ x,
                                                 float* __restrict__ sums) {
    int t  = threadIdx.x;
    int co = (t & 15) * 8;     // column octet
    int rg = t >> 4;           // 0..15
    float s[8], s2[8];
#pragma unroll
    for (int j = 0; j < 8; ++j) { s[j] = 0.f; s2[j] = 0.f; }
    for (int r = blockIdx.x * 16 + rg; r < NN; r += gridDim.x * 16) {
        ushort8 v = *(const ushort8*)(x + (size_t)r * DD + co);
#pragma unroll
        for (int j = 0; j < 8; ++j) {
            float f = bf2f(v[j]);
            s[j] += f; s2[j] += f * f;
        }
    }
    __shared__ float red[16][128];
#pragma unroll
    for (int j = 0; j < 8; ++j) red[rg][co + j] = s[j];
    __syncthreads();
    if (t < 128) {
        float a = 0.f;
#pragma unroll
        for (int g = 0; g < 16; ++g) a += red[g][t];
        atomicAdd(&sums[t], a);
    }
    __syncthreads();
#pragma unroll
    for (int j = 0; j < 8; ++j) red[rg][co + j] = s2[j];
    __syncthreads();
    if (t < 128) {
        float a = 0.f;
#pragma unroll
        for (int g = 0; g < 16; ++g) a += red[g][t];
        atomicAdd(&sums[128 + t], a);
    }
}

// ---------------- BN coefficients ----------------
__global__ void bncoef_k(const float* __restrict__ sums,
                         const float* __restrict__ gamma,
                         const float* __restrict__ beta,
                         float* __restrict__ coefs) {
    int c = threadIdx.x;
    if (c >= DD) return;
    const float n = (float)NN;
    float m  = sums[c] / n;
    float v  = sums[128 + c] / n - m * m;
    float is = rsqrtf(v + 1e-5f);
    float sc = gamma[c] * is;
    coefs[c] = sc;
    coefs[128 + c] = beta[c] - m * sc;
}

// ---------------- ratings: wave per pair, BN2+relu inline (bf16 x) ----------
__global__ __launch_bounds__(256) void ratings_k(const unsigned short* __restrict__ x,
                                                 const int* __restrict__ srcn,
                                                 const int* __restrict__ dstn,
                                                 const float* __restrict__ coefs,
                                                 float* __restrict__ out) {
    int wid  = (blockIdx.x * 256 + threadIdx.x) >> 6;
    int lane = threadIdx.x & 63;
    if (wid >= BB) return;
    int u = srcn[wid], v = dstn[wid];
    const ushort2* xp = (const ushort2*)x;
    ushort2 a = xp[(size_t)u * 64 + lane];
    ushort2 b = xp[(size_t)v * 64 + lane];
    float2 sc = ((const float2*)coefs)[lane];
    float2 sh = ((const float2*)(coefs + 128))[lane];
    float ax = fmaxf(bf2f(a.x) * sc.x + sh.x, 0.f);
    float ay = fmaxf(bf2f(a.y) * sc.y + sh.y, 0.f);
    float bx = fmaxf(bf2f(b.x) * sc.x + sh.x, 0.f);
    float by = fmaxf(bf2f(b.y) * sc.y + sh.y, 0.f);
    float acc = ax * bx + ay * by;
#pragma unroll
    for (int off = 32; off; off >>= 1) acc += __shfl_down(acc, off, 64);
    if (lane == 0) out[wid] = acc;
}

extern "C" void kernel_launch(void* const* d_in, const int* in_sizes, int n_in,
                              void* d_out, int out_size, void* d_ws, size_t ws_size,
                              hipStream_t stream) {
    const int*   edge  = (const int*)d_in[0];      // [2,E]
    const int*   esrc  = edge;
    const int*   edst  = edge + EE;
    const int*   srcn  = (const int*)d_in[2];
    const int*   dstn  = (const int*)d_in[3];
    const float* uemb  = (const float*)d_in[4];
    const float* bemb  = (const float*)d_in[5];
    const float* W1    = (const float*)d_in[6];
    // b1 = d_in[7]  (per-column constant, cancels in BN)
    const float* g1    = (const float*)d_in[8];
    const float* be1   = (const float*)d_in[9];
    const float* W2    = (const float*)d_in[10];
    // b2 = d_in[11] (cancels in BN)
    const float* g2    = (const float*)d_in[12];
    const float* be2   = (const float*)d_in[13];
    float* out = (float*)d_out;

    // workspace layout (16B-aligned segments; NN padded to 150016)
    unsigned short* aggb   = (unsigned short*)d_ws;                      // N*D bf16
    unsigned short* hbuf   = aggb + (size_t)NN * DD;                     // N*D bf16
    int*            cnt    = (int*)(hbuf + (size_t)NN * DD);             // 150016
    float*          sums1  = (float*)(cnt + 150016);                     // 256 (zeroed with cnt)
    float*          sums2  = sums1 + 256;                                // 256 (zeroed with cnt)
    int*            rowptr = (int*)(sums2 + 256);                        // 150016 (>= NN+1)
    int*            cur    = rowptr + 150016;                            // 150016
    float*          dis    = (float*)(cur + 150016);                     // 150016
    int2*           sedge  = (int2*)(dis + 150016);                      // EE int2 (scan scratch first)
    short*          Wf1    = (short*)(sedge + EE);                       // 16384 bf16
    short*          Wf2    = Wf1 + 16384;                                // 16384 bf16
    float*          coef1  = (float*)(Wf2 + 16384);                      // 256
    float*          coef2  = coef1 + 256;                                // 256

    const int egrid = (EE + 255) / 256;            // 1954
    const int ggrid = (NN + 63) / 64;              // 2344 MFMA-GEMM blocks
    const int agrid = (NN + 15) / 16;              // 9375 gather blocks (4 rows/wave)
    int* bsum = (int*)sedge;                       // scan scratch (sedge unwritten until fill_k)

    // ---- CSR build + normalization + W fragments ----
    hipMemsetAsync(cnt, 0, (150016 + 512) * sizeof(int), stream);        // cnt + sums1 + sums2
    count_k<<<egrid, 256, 0, stream>>>(edst, cnt);
    scan1_k<<<NBLK, 256, 0, stream>>>(cnt, rowptr, bsum);
    scan2_k<<<1, 1024, 0, stream>>>(bsum);
    scan3_k<<<NBLK, 256, 0, stream>>>(rowptr, bsum, cur, cnt, dis);
    fill_k<<<egrid, 256, 0, stream>>>(esrc, edst, dis, cur, sedge);
    wfrag_k<<<128, 256, 0, stream>>>(W1, W2, Wf1, Wf2);

    // ---- layer 1 ----
    gemm_mfma_k<0><<<ggrid, 256, 0, stream>>>(uemb, bemb, NUSERS, nullptr, nullptr, Wf1, hbuf);
    gather_k<<<agrid, 256, 0, stream>>>(hbuf, sedge, rowptr, dis, aggb);
    bnstats_k<<<512, 256, 0, stream>>>(aggb, sums1);
    bncoef_k<<<1, 128, 0, stream>>>(sums1, g1, be1, coef1);

    // ---- layer 2 (BN1+relu fused into GEMM A-load, bf16 A) ----
    gemm_mfma_k<1><<<ggrid, 256, 0, stream>>>(nullptr, nullptr, 0, aggb, coef1, Wf2, hbuf);
    gather_k<<<agrid, 256, 0, stream>>>(hbuf, sedge, rowptr, dis, aggb);
    bnstats_k<<<512, 256, 0, stream>>>(aggb, sums2);
    bncoef_k<<<1, 128, 0, stream>>>(sums2, g2, be2, coef2);

    // ---- ratings (BN2+relu inline) ----
    ratings_k<<<BB / 4, 256, 0, stream>>>(aggb, srcn, dstn, coef2, out);
}

// Round 7
// 247.025 us; speedup vs baseline: 1.0004x; 1.0004x over previous
//
#include <hip/hip_runtime.h>
#include <hip/hip_bf16.h>

#define NN      150000
#define NUSERS  50000
#define DD      128
#define EE      500000
#define BB      16384
#define NBLK    586          // ceil(NN/256)

using short8  = __attribute__((ext_vector_type(8))) short;
using ushort8 = __attribute__((ext_vector_type(8))) unsigned short;
using f32x4   = __attribute__((ext_vector_type(4))) float;

__device__ __forceinline__ short f2bf(float v) {
    __hip_bfloat16 b = __float2bfloat16(v);      // RNE; pairs fuse to v_cvt_pk_bf16_f32
    return __builtin_bit_cast(short, b);
}
__device__ __forceinline__ float bf2f(unsigned short b) {
    return __uint_as_float(((unsigned)b) << 16);
}

// ---------------- degree count (int) ----------------
__global__ __launch_bounds__(256) void count_k(const int* __restrict__ dst,
                                               int* __restrict__ cnt) {
    int e = blockIdx.x * 256 + threadIdx.x;
    if (e < EE) atomicAdd(&cnt[dst[e]], 1);
}

// ---------------- hierarchical exclusive scan of cnt -> rowptr ----------------
__global__ __launch_bounds__(256) void scan1_k(const int* __restrict__ cnt,
                                               int* __restrict__ rowptr,
                                               int* __restrict__ bsum) {
    __shared__ int s[256];
    int t = threadIdx.x;
    int i = blockIdx.x * 256 + t;
    int v = (i < NN) ? cnt[i] : 0;
    s[t] = v; __syncthreads();
    for (int off = 1; off < 256; off <<= 1) {
        int x = (t >= off) ? s[t - off] : 0;
        __syncthreads();
        s[t] += x;
        __syncthreads();
    }
    if (i < NN) rowptr[i] = s[t] - v;           // block-local exclusive
    if (t == 255) bsum[blockIdx.x] = s[255];
}

__global__ __launch_bounds__(1024) void scan2_k(int* __restrict__ bsum) {
    __shared__ int s[1024];
    int t = threadIdx.x;
    int v = (t < NBLK) ? bsum[t] : 0;
    s[t] = v; __syncthreads();
    for (int off = 1; off < 1024; off <<= 1) {
        int x = (t >= off) ? s[t - off] : 0;
        __syncthreads();
        s[t] += x;
        __syncthreads();
    }
    if (t < NBLK) bsum[t] = s[t] - v;           // exclusive block offsets
}

// scan3 + dis fused
__global__ __launch_bounds__(256) void scan3_k(int* __restrict__ rowptr,
                                               const int* __restrict__ bsum,
                                               int* __restrict__ cur,
                                               const int* __restrict__ cnt,
                                               float* __restrict__ dis) {
    int i = blockIdx.x * 256 + threadIdx.x;
    if (i < NN) {
        int v = rowptr[i] + bsum[blockIdx.x];
        rowptr[i] = v;
        cur[i] = v;
        dis[i] = rsqrtf((float)cnt[i] + 1.0f);
    }
    if (i == 0) rowptr[NN] = EE;
}

// ---------------- CSR fill (counting sort by dst), packed (src, dis[src]) ----
__global__ __launch_bounds__(256) void fill_k(const int* __restrict__ src,
                                              const int* __restrict__ dst,
                                              const float* __restrict__ dis,
                                              int* __restrict__ cur,
                                              int2* __restrict__ sedge) {
    int e = blockIdx.x * 256 + threadIdx.x;
    if (e < EE) {
        int d = dst[e], s = src[e];
        int pos = atomicAdd(&cur[d], 1);
        sedge[pos] = make_int2(s, __float_as_int(dis[s]));
    }
}

// ---------------- Wfrag prep: per-lane MFMA fragments, bf16 ----------------
// F[((ct*4 + kk)*64 + lane)*8 + e] = W[kk*32 + (lane>>4)*8 + e][ct*16 + (lane&15)]
// Serves as the MFMA A-operand in the swapped scheme.
__global__ __launch_bounds__(256) void wfrag_k(const float* __restrict__ W1,
                                               const float* __restrict__ W2,
                                               short* __restrict__ F1,
                                               short* __restrict__ F2) {
    int idx = blockIdx.x * 256 + threadIdx.x;   // [0, 32768)
    int m = idx >> 14;
    int i = idx & 16383;
    int e  = i & 7;
    int l  = (i >> 3) & 63;
    int kk = (i >> 9) & 3;
    int ct = i >> 11;
    int k = kk * 32 + (l >> 4) * 8 + e;
    int c = ct * 16 + (l & 15);
    const float* W = m ? W2 : W1;
    short*       F = m ? F2 : F1;
    F[i] = f2bf(W[k * DD + c]);
}

// ---------------- MFMA GEMM (swapped operands, 64 rows/wave): hout = A @ W --
// MODE 0: A = concat(A0[0:nsplit], A1) fp32, raw.            Layer 1.
// MODE 1: A = relu(bf16(Ab) * coefs[c] + coefs[128+c]).      Layer 2.
// Each wave: 4 row-groups x 16 rows = 64 rows, all 128 cols.
// Per kk: 8 Wfrag loads feed 32 MFMAs (4 rows-groups each) -> 128 MFMA/wave,
// 32 independent acc chains.  D[m][n]: lane holds row = n (fixed per rg),
// cols ct*16 + kgrp*4 + j consecutive -> 8B packed stores.
template<int MODE>
__global__ __launch_bounds__(256) void gemm_mfma_k(const float* __restrict__ A0,
                                                   const float* __restrict__ A1,
                                                   int nsplit,
                                                   const unsigned short* __restrict__ Ab,
                                                   const float* __restrict__ coefs,
                                                   const short* __restrict__ Wfrag,
                                                   unsigned short* __restrict__ hout) {
    int wave = threadIdx.x >> 6;
    int lane = threadIdx.x & 63;
    int kgrp = lane >> 4;        // 0..3
    int lrow = lane & 15;
    int r0 = blockIdx.x * 256 + wave * 64;

    const float* arow[4];
    const unsigned short* brow[4];
#pragma unroll
    for (int rg = 0; rg < 4; ++rg) {
        int r = r0 + rg * 16 + lrow;
        int lr = r > NN - 1 ? NN - 1 : r;
        if (MODE == 0) arow[rg] = (lr < nsplit) ? A0 + (size_t)lr * DD
                                                : A1 + (size_t)(lr - nsplit) * DD;
        else           brow[rg] = Ab + (size_t)lr * DD;
    }

    f32x4 acc[8][4];             // [ct][rg]
#pragma unroll
    for (int ct = 0; ct < 8; ++ct)
#pragma unroll
        for (int rg = 0; rg < 4; ++rg) acc[ct][rg] = (f32x4){0.f, 0.f, 0.f, 0.f};

    const short8* wf = (const short8*)Wfrag;

#pragma unroll
    for (int kk = 0; kk < 4; ++kk) {
        int d0 = kk * 32 + kgrp * 8;
        short8 rfrag[4];
        if (MODE == 1) {
            f32x4 s1 = *(const f32x4*)(coefs + d0);
            f32x4 s2 = *(const f32x4*)(coefs + d0 + 4);
            f32x4 t1 = *(const f32x4*)(coefs + 128 + d0);
            f32x4 t2 = *(const f32x4*)(coefs + 128 + d0 + 4);
#pragma unroll
            for (int rg = 0; rg < 4; ++rg) {
                ushort8 u = *(const ushort8*)(brow[rg] + d0);
#pragma unroll
                for (int j = 0; j < 4; ++j) {
                    rfrag[rg][j]     = f2bf(fmaxf(bf2f(u[j])     * s1[j] + t1[j], 0.f));
                    rfrag[rg][4 + j] = f2bf(fmaxf(bf2f(u[4 + j]) * s2[j] + t2[j], 0.f));
                }
            }
        } else {
#pragma unroll
            for (int rg = 0; rg < 4; ++rg) {
                f32x4 va = *(const f32x4*)(arow[rg] + d0);
                f32x4 vb = *(const f32x4*)(arow[rg] + d0 + 4);
#pragma unroll
                for (int j = 0; j < 4; ++j) {
                    rfrag[rg][j]     = f2bf(va[j]);
                    rfrag[rg][4 + j] = f2bf(vb[j]);
                }
            }
        }
#pragma unroll
        for (int ct = 0; ct < 8; ++ct) {
            short8 wfr = wf[(ct * 4 + kk) * 64 + lane];
#pragma unroll
            for (int rg = 0; rg < 4; ++rg)
                acc[ct][rg] = __builtin_amdgcn_mfma_f32_16x16x32_bf16(wfr, rfrag[rg],
                                                                      acc[ct][rg], 0, 0, 0);
        }
    }

#pragma unroll
    for (int rg = 0; rg < 4; ++rg) {
        int row = r0 + rg * 16 + lrow;
        if (row < NN) {
            size_t rb = (size_t)row * DD;
#pragma unroll
            for (int ct = 0; ct < 8; ++ct) {
                int col = ct * 16 + kgrp * 4;
                unsigned p0 = (unsigned)(unsigned short)f2bf(acc[ct][rg][0])
                            | ((unsigned)(unsigned short)f2bf(acc[ct][rg][1]) << 16);
                unsigned p1 = (unsigned)(unsigned short)f2bf(acc[ct][rg][2])
                            | ((unsigned)(unsigned short)f2bf(acc[ct][rg][3]) << 16);
                uint2 p; p.x = p0; p.y = p1;
                *(uint2*)(hout + rb + col) = p;
            }
        }
    }
}

// ---------------- CSR gather: 4 rows per wave (16-lane groups, ushort8) -----
// aggb[i] = bf16( dis[i]*sum(dis[s]*h[s]) + dis[i]^2*h[i] )
__global__ __launch_bounds__(256) void gather_k(const unsigned short* __restrict__ h,
                                                const int2* __restrict__ se,
                                                const int* __restrict__ rowptr,
                                                const float* __restrict__ dis,
                                                unsigned short* __restrict__ aggb) {
    int t = threadIdx.x;
    int l = t & 15;                       // lane within row-group (8 cols each)
    int row = blockIdx.x * 16 + (t >> 4); // 16 rows per block (4 per wave)
    if (row >= NN) return;
    int p0 = rowptr[row], p1 = rowptr[row + 1];
    const ushort8* hp = (const ushort8*)h;

    float acc[8];
#pragma unroll
    for (int j = 0; j < 8; ++j) acc[j] = 0.f;

    for (int base = p0; base < p1; base += 4) {
        int i1 = min(base + 1, p1 - 1);
        int i2 = min(base + 2, p1 - 1);
        int i3 = min(base + 3, p1 - 1);
        int2 e0 = se[base], e1 = se[i1], e2 = se[i2], e3 = se[i3];
        ushort8 h0 = hp[(size_t)e0.x * 16 + l];
        ushort8 h1 = hp[(size_t)e1.x * 16 + l];
        ushort8 h2 = hp[(size_t)e2.x * 16 + l];
        ushort8 h3 = hp[(size_t)e3.x * 16 + l];
        float w0 = __int_as_float(e0.y);
        float w1 = (base + 1 < p1) ? __int_as_float(e1.y) : 0.f;
        float w2 = (base + 2 < p1) ? __int_as_float(e2.y) : 0.f;
        float w3 = (base + 3 < p1) ? __int_as_float(e3.y) : 0.f;
#pragma unroll
        for (int j = 0; j < 8; ++j) {
            acc[j] += w0 * bf2f(h0[j]) + w1 * bf2f(h1[j])
                    + w2 * bf2f(h2[j]) + w3 * bf2f(h3[j]);
        }
    }
    float d  = dis[row];
    float d2 = d * d;
    ushort8 hs = hp[(size_t)row * 16 + l];
    ushort8 o;
#pragma unroll
    for (int j = 0; j < 8; ++j)
        o[j] = (unsigned short)f2bf(d * acc[j] + d2 * bf2f(hs[j]));
    ((ushort8*)aggb)[(size_t)row * 16 + l] = o;
}

// ---------------- BN stats on bf16 x: per-column sum & sumsq ----------------
__global__ __launch_bounds__(256) void bnstats_k(const unsigned short* __restrict__ x,
                                                 float* __restrict__ sums) {
    int t  = threadIdx.x;
    int co = (t & 15) * 8;     // column octet
    int rg = t >> 4;           // 0..15
    float s[8], s2[8];
#pragma unroll
    for (int j = 0; j < 8; ++j) { s[j] = 0.f; s2[j] = 0.f; }
    for (int r = blockIdx.x * 16 + rg; r < NN; r += gridDim.x * 16) {
        ushort8 v = *(const ushort8*)(x + (size_t)r * DD + co);
#pragma unroll
        for (int j = 0; j < 8; ++j) {
            float f = bf2f(v[j]);
            s[j] += f; s2[j] += f * f;
        }
    }
    __shared__ float red[16][128];
#pragma unroll
    for (int j = 0; j < 8; ++j) red[rg][co + j] = s[j];
    __syncthreads();
    if (t < 128) {
        float a = 0.f;
#pragma unroll
        for (int g = 0; g < 16; ++g) a += red[g][t];
        atomicAdd(&sums[t], a);
    }
    __syncthreads();
#pragma unroll
    for (int j = 0; j < 8; ++j) red[rg][co + j] = s2[j];
    __syncthreads();
    if (t < 128) {
        float a = 0.f;
#pragma unroll
        for (int g = 0; g < 16; ++g) a += red[g][t];
        atomicAdd(&sums[128 + t], a);
    }
}

// ---------------- BN coefficients ----------------
__global__ void bncoef_k(const float* __restrict__ sums,
                         const float* __restrict__ gamma,
                         const float* __restrict__ beta,
                         float* __restrict__ coefs) {
    int c = threadIdx.x;
    if (c >= DD) return;
    const float n = (float)NN;
    float m  = sums[c] / n;
    float v  = sums[128 + c] / n - m * m;
    float is = rsqrtf(v + 1e-5f);
    float sc = gamma[c] * is;
    coefs[c] = sc;
    coefs[128 + c] = beta[c] - m * sc;
}

// ---------------- ratings: wave per pair, BN2+relu inline (bf16 x) ----------
__global__ __launch_bounds__(256) void ratings_k(const unsigned short* __restrict__ x,
                                                 const int* __restrict__ srcn,
                                                 const int* __restrict__ dstn,
                                                 const float* __restrict__ coefs,
                                                 float* __restrict__ out) {
    int wid  = (blockIdx.x * 256 + threadIdx.x) >> 6;
    int lane = threadIdx.x & 63;
    if (wid >= BB) return;
    int u = srcn[wid], v = dstn[wid];
    const ushort2* xp = (const ushort2*)x;
    ushort2 a = xp[(size_t)u * 64 + lane];
    ushort2 b = xp[(size_t)v * 64 + lane];
    float2 sc = ((const float2*)coefs)[lane];
    float2 sh = ((const float2*)(coefs + 128))[lane];
    float ax = fmaxf(bf2f(a.x) * sc.x + sh.x, 0.f);
    float ay = fmaxf(bf2f(a.y) * sc.y + sh.y, 0.f);
    float bx = fmaxf(bf2f(b.x) * sc.x + sh.x, 0.f);
    float by = fmaxf(bf2f(b.y) * sc.y + sh.y, 0.f);
    float acc = ax * bx + ay * by;
#pragma unroll
    for (int off = 32; off; off >>= 1) acc += __shfl_down(acc, off, 64);
    if (lane == 0) out[wid] = acc;
}

extern "C" void kernel_launch(void* const* d_in, const int* in_sizes, int n_in,
                              void* d_out, int out_size, void* d_ws, size_t ws_size,
                              hipStream_t stream) {
    const int*   edge  = (const int*)d_in[0];      // [2,E]
    const int*   esrc  = edge;
    const int*   edst  = edge + EE;
    const int*   srcn  = (const int*)d_in[2];
    const int*   dstn  = (const int*)d_in[3];
    const float* uemb  = (const float*)d_in[4];
    const float* bemb  = (const float*)d_in[5];
    const float* W1    = (const float*)d_in[6];
    // b1 = d_in[7]  (per-column constant, cancels in BN)
    const float* g1    = (const float*)d_in[8];
    const float* be1   = (const float*)d_in[9];
    const float* W2    = (const float*)d_in[10];
    // b2 = d_in[11] (cancels in BN)
    const float* g2    = (const float*)d_in[12];
    const float* be2   = (const float*)d_in[13];
    float* out = (float*)d_out;

    // workspace layout (16B-aligned segments; NN padded to 150016)
    unsigned short* aggb   = (unsigned short*)d_ws;                      // N*D bf16
    unsigned short* hbuf   = aggb + (size_t)NN * DD;                     // N*D bf16
    int*            cnt    = (int*)(hbuf + (size_t)NN * DD);             // 150016
    float*          sums1  = (float*)(cnt + 150016);                     // 256 (zeroed with cnt)
    float*          sums2  = sums1 + 256;                                // 256 (zeroed with cnt)
    int*            rowptr = (int*)(sums2 + 256);                        // 150016 (>= NN+1)
    int*            cur    = rowptr + 150016;                            // 150016
    float*          dis    = (float*)(cur + 150016);                     // 150016
    int2*           sedge  = (int2*)(dis + 150016);                      // EE int2 (scan scratch first)
    short*          Wf1    = (short*)(sedge + EE);                       // 16384 bf16
    short*          Wf2    = Wf1 + 16384;                                // 16384 bf16
    float*          coef1  = (float*)(Wf2 + 16384);                      // 256
    float*          coef2  = coef1 + 256;                                // 256

    const int egrid = (EE + 255) / 256;            // 1954
    const int ggrid = (NN + 255) / 256;            // 586 MFMA-GEMM blocks (256 rows each)
    const int agrid = (NN + 15) / 16;              // 9375 gather blocks (4 rows/wave)
    int* bsum = (int*)sedge;                       // scan scratch (sedge unwritten until fill_k)

    // ---- CSR build + normalization + W fragments ----
    hipMemsetAsync(cnt, 0, (150016 + 512) * sizeof(int), stream);        // cnt + sums1 + sums2
    count_k<<<egrid, 256, 0, stream>>>(edst, cnt);
    scan1_k<<<NBLK, 256, 0, stream>>>(cnt, rowptr, bsum);
    scan2_k<<<1, 1024, 0, stream>>>(bsum);
    scan3_k<<<NBLK, 256, 0, stream>>>(rowptr, bsum, cur, cnt, dis);
    fill_k<<<egrid, 256, 0, stream>>>(esrc, edst, dis, cur, sedge);
    wfrag_k<<<128, 256, 0, stream>>>(W1, W2, Wf1, Wf2);

    // ---- layer 1 ----
    gemm_mfma_k<0><<<ggrid, 256, 0, stream>>>(uemb, bemb, NUSERS, nullptr, nullptr, Wf1, hbuf);
    gather_k<<<agrid, 256, 0, stream>>>(hbuf, sedge, rowptr, dis, aggb);
    bnstats_k<<<512, 256, 0, stream>>>(aggb, sums1);
    bncoef_k<<<1, 128, 0, stream>>>(sums1, g1, be1, coef1);

    // ---- layer 2 (BN1+relu fused into GEMM A-load, bf16 A) ----
    gemm_mfma_k<1><<<ggrid, 256, 0, stream>>>(nullptr, nullptr, 0, aggb, coef1, Wf2, hbuf);
    gather_k<<<agrid, 256, 0, stream>>>(hbuf, sedge, rowptr, dis, aggb);
    bnstats_k<<<512, 256, 0, stream>>>(aggb, sums2);
    bncoef_k<<<1, 128, 0, stream>>>(sums2, g2, be2, coef2);

    // ---- ratings (BN2+relu inline) ----
    ratings_k<<<BB / 4, 256, 0, stream>>>(aggb, srcn, dstn, coef2, out);
}

// Round 8
// 230.115 us; speedup vs baseline: 1.0739x; 1.0735x over previous
//
#include <hip/hip_runtime.h>
#include <hip/hip_bf16.h>

#define NN      150000
#define NUSERS  50000
#define DD      128
#define EE      500000
#define BB      16384
#define NBLK    586          // ceil(NN/256)

using short8  = __attribute__((ext_vector_type(8))) short;
using ushort8 = __attribute__((ext_vector_type(8))) unsigned short;
using f32x4   = __attribute__((ext_vector_type(4))) float;

typedef __attribute__((address_space(1))) const unsigned int glb_u32;
typedef __attribute__((address_space(3))) unsigned int       lds_u32;

__device__ __forceinline__ short f2bf(float v) {
    __hip_bfloat16 b = __float2bfloat16(v);      // RNE; pairs fuse to v_cvt_pk_bf16_f32
    return __builtin_bit_cast(short, b);
}
__device__ __forceinline__ float bf2f(unsigned short b) {
    return __uint_as_float(((unsigned)b) << 16);
}

// ---------------- degree count (int) ----------------
__global__ __launch_bounds__(256) void count_k(const int* __restrict__ dst,
                                               int* __restrict__ cnt) {
    int e = blockIdx.x * 256 + threadIdx.x;
    if (e < EE) atomicAdd(&cnt[dst[e]], 1);
}

// ---------------- hierarchical exclusive scan of cnt -> rowptr ----------------
__global__ __launch_bounds__(256) void scan1_k(const int* __restrict__ cnt,
                                               int* __restrict__ rowptr,
                                               int* __restrict__ bsum) {
    __shared__ int s[256];
    int t = threadIdx.x;
    int i = blockIdx.x * 256 + t;
    int v = (i < NN) ? cnt[i] : 0;
    s[t] = v; __syncthreads();
    for (int off = 1; off < 256; off <<= 1) {
        int x = (t >= off) ? s[t - off] : 0;
        __syncthreads();
        s[t] += x;
        __syncthreads();
    }
    if (i < NN) rowptr[i] = s[t] - v;           // block-local exclusive
    if (t == 255) bsum[blockIdx.x] = s[255];
}

__global__ __launch_bounds__(1024) void scan2_k(int* __restrict__ bsum) {
    __shared__ int s[1024];
    int t = threadIdx.x;
    int v = (t < NBLK) ? bsum[t] : 0;
    s[t] = v; __syncthreads();
    for (int off = 1; off < 1024; off <<= 1) {
        int x = (t >= off) ? s[t - off] : 0;
        __syncthreads();
        s[t] += x;
        __syncthreads();
    }
    if (t < NBLK) bsum[t] = s[t] - v;           // exclusive block offsets
}

// scan3 + dis fused
__global__ __launch_bounds__(256) void scan3_k(int* __restrict__ rowptr,
                                               const int* __restrict__ bsum,
                                               int* __restrict__ cur,
                                               const int* __restrict__ cnt,
                                               float* __restrict__ dis) {
    int i = blockIdx.x * 256 + threadIdx.x;
    if (i < NN) {
        int v = rowptr[i] + bsum[blockIdx.x];
        rowptr[i] = v;
        cur[i] = v;
        dis[i] = rsqrtf((float)cnt[i] + 1.0f);
    }
    if (i == 0) rowptr[NN] = EE;
}

// ---------------- CSR fill (counting sort by dst), packed (src, dis[src]) ----
__global__ __launch_bounds__(256) void fill_k(const int* __restrict__ src,
                                              const int* __restrict__ dst,
                                              const float* __restrict__ dis,
                                              int* __restrict__ cur,
                                              int2* __restrict__ sedge) {
    int e = blockIdx.x * 256 + threadIdx.x;
    if (e < EE) {
        int d = dst[e], s = src[e];
        int pos = atomicAdd(&cur[d], 1);
        sedge[pos] = make_int2(s, __float_as_int(dis[s]));
    }
}

// ---------------- Wfrag prep: per-lane MFMA fragments, bf16 ----------------
// F[((ct*4 + kk)*64 + lane)*8 + e] = W[kk*32 + (lane>>4)*8 + e][ct*16 + (lane&15)]
// Serves as the MFMA A-operand in the swapped scheme.
__global__ __launch_bounds__(256) void wfrag_k(const float* __restrict__ W1,
                                               const float* __restrict__ W2,
                                               short* __restrict__ F1,
                                               short* __restrict__ F2) {
    int idx = blockIdx.x * 256 + threadIdx.x;   // [0, 32768)
    int m = idx >> 14;
    int i = idx & 16383;
    int e  = i & 7;
    int l  = (i >> 3) & 63;
    int kk = (i >> 9) & 3;
    int ct = i >> 11;
    int k = kk * 32 + (l >> 4) * 8 + e;
    int c = ct * 16 + (l & 15);
    const float* W = m ? W2 : W1;
    short*       F = m ? F2 : F1;
    F[i] = f2bf(W[k * DD + c]);
}

// ---------------- MFMA GEMM, LDS-staged via global_load_lds ----------------
// MODE 0: A = concat(A0[0:nsplit], A1) fp32, raw.            Layer 1.
// MODE 1: A = relu(bf16(Ab) * coefs[c] + coefs[128+c]).      Layer 2.
// One 64-row tile per block. Whole tile staged to LDS with width-16
// global_load_lds (no VGPR pressure -> deep load queue). LDS row stride is
// padded (528B fp32 / 272B bf16; stride%128B==16B) so the 16-row column read
// spreads across 8 bank slots (~2 lanes/bank, free per m136).
template<int MODE>
__global__ __launch_bounds__(256) void gemm_mfma_k(const float* __restrict__ A0,
                                                   const float* __restrict__ A1,
                                                   int nsplit,
                                                   const unsigned short* __restrict__ Ab,
                                                   const float* __restrict__ coefs,
                                                   const short* __restrict__ Wfrag,
                                                   unsigned short* __restrict__ hout) {
    constexpr int ROWB  = (MODE == 0) ? 528 : 272;   // padded LDS row stride (bytes)
    constexpr int PAY   = (MODE == 0) ? 512 : 256;   // payload bytes per row
    constexpr int TILEB = 64 * ROWB;
    constexpr int NCH   = TILEB / 16;                // 16B chunks (2112 / 1088)
    constexpr int FULLR = NCH / 256;                 // full staging rounds (8 / 4)

    __shared__ __align__(16) char smem[TILEB];

    int t    = threadIdx.x;
    int wave = t >> 6;
    int lane = t & 63;
    int kgrp = lane >> 4;        // 0..3
    int lrow = lane & 15;
    int r0   = blockIdx.x * 64;

    // ---- stage tile into LDS ----
#pragma unroll
    for (int r = 0; r < FULLR; ++r) {
        int chunk = r * 256 + t;
        int o     = chunk * 16;
        int row   = o / ROWB;
        int inner = o - row * ROWB;
        if (inner >= PAY) inner = 0;                 // padding chunk: safe in-row read
        int gr = r0 + row; if (gr > NN - 1) gr = NN - 1;
        const char* src;
        if (MODE == 0) src = (const char*)((gr < nsplit) ? (A0 + (size_t)gr * DD)
                                                         : (A1 + (size_t)(gr - nsplit) * DD)) + inner;
        else           src = (const char*)(Ab + (size_t)gr * DD) + inner;
        lds_u32* dst = (lds_u32*)(smem + r * 4096 + wave * 1024);  // wave-uniform base
        __builtin_amdgcn_global_load_lds((glb_u32*)src, dst, 16, 0, 0);
    }
    if (wave == 0) {                                 // remaining 64 chunks
        int chunk = FULLR * 256 + lane;
        int o     = chunk * 16;
        int row   = o / ROWB;
        int inner = o - row * ROWB;
        if (inner >= PAY) inner = 0;
        int gr = r0 + row; if (gr > NN - 1) gr = NN - 1;
        const char* src;
        if (MODE == 0) src = (const char*)((gr < nsplit) ? (A0 + (size_t)gr * DD)
                                                         : (A1 + (size_t)(gr - nsplit) * DD)) + inner;
        else           src = (const char*)(Ab + (size_t)gr * DD) + inner;
        lds_u32* dst = (lds_u32*)(smem + FULLR * 4096);
        __builtin_amdgcn_global_load_lds((glb_u32*)src, dst, 16, 0, 0);
    }
    __syncthreads();   // drains vmcnt(0): staged tile visible

    // ---- compute: 16 rows/wave, all 128 cols ----
    const char* arow = smem + (wave * 16 + lrow) * ROWB;

    f32x4 acc[8];
#pragma unroll
    for (int ct = 0; ct < 8; ++ct) acc[ct] = (f32x4){0.f, 0.f, 0.f, 0.f};

    const short8* wf = (const short8*)Wfrag;

#pragma unroll
    for (int kk = 0; kk < 4; ++kk) {
        short8 rfrag;
        if (MODE == 0) {
            f32x4 va = *(const f32x4*)(arow + kk * 128 + kgrp * 32);
            f32x4 vb = *(const f32x4*)(arow + kk * 128 + kgrp * 32 + 16);
#pragma unroll
            for (int j = 0; j < 4; ++j) { rfrag[j] = f2bf(va[j]); rfrag[4 + j] = f2bf(vb[j]); }
        } else {
            int d0 = kk * 32 + kgrp * 8;
            ushort8 u = *(const ushort8*)(arow + kk * 64 + kgrp * 16);
            f32x4 s1 = *(const f32x4*)(coefs + d0);
            f32x4 s2 = *(const f32x4*)(coefs + d0 + 4);
            f32x4 t1 = *(const f32x4*)(coefs + 128 + d0);
            f32x4 t2 = *(const f32x4*)(coefs + 128 + d0 + 4);
#pragma unroll
            for (int j = 0; j < 4; ++j) {
                rfrag[j]     = f2bf(fmaxf(bf2f(u[j])     * s1[j] + t1[j], 0.f));
                rfrag[4 + j] = f2bf(fmaxf(bf2f(u[4 + j]) * s2[j] + t2[j], 0.f));
            }
        }
#pragma unroll
        for (int ct = 0; ct < 8; ++ct) {
            short8 wfr = wf[(ct * 4 + kk) * 64 + lane];
            acc[ct] = __builtin_amdgcn_mfma_f32_16x16x32_bf16(wfr, rfrag, acc[ct], 0, 0, 0);
        }
    }

    // D layout (swapped operands): lane holds row = r0+wave*16+lrow fixed,
    // cols = ct*16 + kgrp*4 + j  (consecutive) -> 8B packed stores.
    int row = r0 + wave * 16 + lrow;
    if (row < NN) {
        size_t rb = (size_t)row * DD;
#pragma unroll
        for (int ct = 0; ct < 8; ++ct) {
            int col = ct * 16 + kgrp * 4;
            unsigned p0 = (unsigned)(unsigned short)f2bf(acc[ct][0])
                        | ((unsigned)(unsigned short)f2bf(acc[ct][1]) << 16);
            unsigned p1 = (unsigned)(unsigned short)f2bf(acc[ct][2])
                        | ((unsigned)(unsigned short)f2bf(acc[ct][3]) << 16);
            uint2 p; p.x = p0; p.y = p1;
            *(uint2*)(hout + rb + col) = p;
        }
    }
}

// ---------------- CSR gather: 4 rows per wave (16-lane groups, ushort8) -----
// aggb[i] = bf16( dis[i]*sum(dis[s]*h[s]) + dis[i]^2*h[i] )
__global__ __launch_bounds__(256) void gather_k(const unsigned short* __restrict__ h,
                                                const int2* __restrict__ se,
                                                const int* __restrict__ rowptr,
                                                const float* __restrict__ dis,
                                                unsigned short* __restrict__ aggb) {
    int t = threadIdx.x;
    int l = t & 15;                       // lane within row-group (8 cols each)
    int row = blockIdx.x * 16 + (t >> 4); // 16 rows per block (4 per wave)
    if (row >= NN) return;
    int p0 = rowptr[row], p1 = rowptr[row + 1];
    const ushort8* hp = (const ushort8*)h;

    float acc[8];
#pragma unroll
    for (int j = 0; j < 8; ++j) acc[j] = 0.f;

    for (int base = p0; base < p1; base += 4) {
        int i1 = min(base + 1, p1 - 1);
        int i2 = min(base + 2, p1 - 1);
        int i3 = min(base + 3, p1 - 1);
        int2 e0 = se[base], e1 = se[i1], e2 = se[i2], e3 = se[i3];
        ushort8 h0 = hp[(size_t)e0.x * 16 + l];
        ushort8 h1 = hp[(size_t)e1.x * 16 + l];
        ushort8 h2 = hp[(size_t)e2.x * 16 + l];
        ushort8 h3 = hp[(size_t)e3.x * 16 + l];
        float w0 = __int_as_float(e0.y);
        float w1 = (base + 1 < p1) ? __int_as_float(e1.y) : 0.f;
        float w2 = (base + 2 < p1) ? __int_as_float(e2.y) : 0.f;
        float w3 = (base + 3 < p1) ? __int_as_float(e3.y) : 0.f;
#pragma unroll
        for (int j = 0; j < 8; ++j) {
            acc[j] += w0 * bf2f(h0[j]) + w1 * bf2f(h1[j])
                    + w2 * bf2f(h2[j]) + w3 * bf2f(h3[j]);
        }
    }
    float d  = dis[row];
    float d2 = d * d;
    ushort8 hs = hp[(size_t)row * 16 + l];
    ushort8 o;
#pragma unroll
    for (int j = 0; j < 8; ++j)
        o[j] = (unsigned short)f2bf(d * acc[j] + d2 * bf2f(hs[j]));
    ((ushort8*)aggb)[(size_t)row * 16 + l] = o;
}

// ---------------- BN stats on bf16 x: per-column sum & sumsq ----------------
__global__ __launch_bounds__(256) void bnstats_k(const unsigned short* __restrict__ x,
                                                 float* __restrict__ sums) {
    int t  = threadIdx.x;
    int co = (t & 15) * 8;     // column octet
    int rg = t >> 4;           // 0..15
    float s[8], s2[8];
#pragma unroll
    for (int j = 0; j < 8; ++j) { s[j] = 0.f; s2[j] = 0.f; }
    for (int r = blockIdx.x * 16 + rg; r < NN; r += gridDim.x * 16) {
        ushort8 v = *(const ushort8*)(x + (size_t)r * DD + co);
#pragma unroll
        for (int j = 0; j < 8; ++j) {
            float f = bf2f(v[j]);
            s[j] += f; s2[j] += f * f;
        }
    }
    __shared__ float red[16][128];
#pragma unroll
    for (int j = 0; j < 8; ++j) red[rg][co + j] = s[j];
    __syncthreads();
    if (t < 128) {
        float a = 0.f;
#pragma unroll
        for (int g = 0; g < 16; ++g) a += red[g][t];
        atomicAdd(&sums[t], a);
    }
    __syncthreads();
#pragma unroll
    for (int j = 0; j < 8; ++j) red[rg][co + j] = s2[j];
    __syncthreads();
    if (t < 128) {
        float a = 0.f;
#pragma unroll
        for (int g = 0; g < 16; ++g) a += red[g][t];
        atomicAdd(&sums[128 + t], a);
    }
}

// ---------------- BN coefficients ----------------
__global__ void bncoef_k(const float* __restrict__ sums,
                         const float* __restrict__ gamma,
                         const float* __restrict__ beta,
                         float* __restrict__ coefs) {
    int c = threadIdx.x;
    if (c >= DD) return;
    const float n = (float)NN;
    float m  = sums[c] / n;
    float v  = sums[128 + c] / n - m * m;
    float is = rsqrtf(v + 1e-5f);
    float sc = gamma[c] * is;
    coefs[c] = sc;
    coefs[128 + c] = beta[c] - m * sc;
}

// ---------------- ratings: wave per pair, BN2+relu inline (bf16 x) ----------
__global__ __launch_bounds__(256) void ratings_k(const unsigned short* __restrict__ x,
                                                 const int* __restrict__ srcn,
                                                 const int* __restrict__ dstn,
                                                 const float* __restrict__ coefs,
                                                 float* __restrict__ out) {
    int wid  = (blockIdx.x * 256 + threadIdx.x) >> 6;
    int lane = threadIdx.x & 63;
    if (wid >= BB) return;
    int u = srcn[wid], v = dstn[wid];
    const ushort2* xp = (const ushort2*)x;
    ushort2 a = xp[(size_t)u * 64 + lane];
    ushort2 b = xp[(size_t)v * 64 + lane];
    float2 sc = ((const float2*)coefs)[lane];
    float2 sh = ((const float2*)(coefs + 128))[lane];
    float ax = fmaxf(bf2f(a.x) * sc.x + sh.x, 0.f);
    float ay = fmaxf(bf2f(a.y) * sc.y + sh.y, 0.f);
    float bx = fmaxf(bf2f(b.x) * sc.x + sh.x, 0.f);
    float by = fmaxf(bf2f(b.y) * sc.y + sh.y, 0.f);
    float acc = ax * bx + ay * by;
#pragma unroll
    for (int off = 32; off; off >>= 1) acc += __shfl_down(acc, off, 64);
    if (lane == 0) out[wid] = acc;
}

extern "C" void kernel_launch(void* const* d_in, const int* in_sizes, int n_in,
                              void* d_out, int out_size, void* d_ws, size_t ws_size,
                              hipStream_t stream) {
    const int*   edge  = (const int*)d_in[0];      // [2,E]
    const int*   esrc  = edge;
    const int*   edst  = edge + EE;
    const int*   srcn  = (const int*)d_in[2];
    const int*   dstn  = (const int*)d_in[3];
    const float* uemb  = (const float*)d_in[4];
    const float* bemb  = (const float*)d_in[5];
    const float* W1    = (const float*)d_in[6];
    // b1 = d_in[7]  (per-column constant, cancels in BN)
    const float* g1    = (const float*)d_in[8];
    const float* be1   = (const float*)d_in[9];
    const float* W2    = (const float*)d_in[10];
    // b2 = d_in[11] (cancels in BN)
    const float* g2    = (const float*)d_in[12];
    const float* be2   = (const float*)d_in[13];
    float* out = (float*)d_out;

    // workspace layout (16B-aligned segments; NN padded to 150016)
    unsigned short* aggb   = (unsigned short*)d_ws;                      // N*D bf16
    unsigned short* hbuf   = aggb + (size_t)NN * DD;                     // N*D bf16
    int*            cnt    = (int*)(hbuf + (size_t)NN * DD);             // 150016
    float*          sums1  = (float*)(cnt + 150016);                     // 256 (zeroed with cnt)
    float*          sums2  = sums1 + 256;                                // 256 (zeroed with cnt)
    int*            rowptr = (int*)(sums2 + 256);                        // 150016 (>= NN+1)
    int*            cur    = rowptr + 150016;                            // 150016
    float*          dis    = (float*)(cur + 150016);                     // 150016
    int2*           sedge  = (int2*)(dis + 150016);                      // EE int2 (scan scratch first)
    short*          Wf1    = (short*)(sedge + EE);                       // 16384 bf16
    short*          Wf2    = Wf1 + 16384;                                // 16384 bf16
    float*          coef1  = (float*)(Wf2 + 16384);                      // 256
    float*          coef2  = coef1 + 256;                                // 256

    const int egrid = (EE + 255) / 256;            // 1954
    const int ggrid = (NN + 63) / 64;              // 2344 MFMA-GEMM blocks (64 rows each)
    const int agrid = (NN + 15) / 16;              // 9375 gather blocks (4 rows/wave)
    int* bsum = (int*)sedge;                       // scan scratch (sedge unwritten until fill_k)

    // ---- CSR build + normalization + W fragments ----
    hipMemsetAsync(cnt, 0, (150016 + 512) * sizeof(int), stream);        // cnt + sums1 + sums2
    count_k<<<egrid, 256, 0, stream>>>(edst, cnt);
    scan1_k<<<NBLK, 256, 0, stream>>>(cnt, rowptr, bsum);
    scan2_k<<<1, 1024, 0, stream>>>(bsum);
    scan3_k<<<NBLK, 256, 0, stream>>>(rowptr, bsum, cur, cnt, dis);
    fill_k<<<egrid, 256, 0, stream>>>(esrc, edst, dis, cur, sedge);
    wfrag_k<<<128, 256, 0, stream>>>(W1, W2, Wf1, Wf2);

    // ---- layer 1 ----
    gemm_mfma_k<0><<<ggrid, 256, 0, stream>>>(uemb, bemb, NUSERS, nullptr, nullptr, Wf1, hbuf);
    gather_k<<<agrid, 256, 0, stream>>>(hbuf, sedge, rowptr, dis, aggb);
    bnstats_k<<<512, 256, 0, stream>>>(aggb, sums1);
    bncoef_k<<<1, 128, 0, stream>>>(sums1, g1, be1, coef1);

    // ---- layer 2 (BN1+relu fused into GEMM A-load, bf16 A) ----
    gemm_mfma_k<1><<<ggrid, 256, 0, stream>>>(nullptr, nullptr, 0, aggb, coef1, Wf2, hbuf);
    gather_k<<<agrid, 256, 0, stream>>>(hbuf, sedge, rowptr, dis, aggb);
    bnstats_k<<<512, 256, 0, stream>>>(aggb, sums2);
    bncoef_k<<<1, 128, 0, stream>>>(sums2, g2, be2, coef2);

    // ---- ratings (BN2+relu inline) ----
    ratings_k<<<BB / 4, 256, 0, stream>>>(aggb, srcn, dstn, coef2, out);
}

// Round 9
// 218.907 us; speedup vs baseline: 1.1288x; 1.0512x over previous
//
#include <hip/hip_runtime.h>
#include <hip/hip_bf16.h>

#define NN      150000
#define NUSERS  50000
#define DD      128
#define EE      500000
#define BB      16384
#define NBLK    586          // ceil(NN/256)

using short8  = __attribute__((ext_vector_type(8))) short;
using ushort8 = __attribute__((ext_vector_type(8))) unsigned short;
using f32x4   = __attribute__((ext_vector_type(4))) float;

typedef __attribute__((address_space(1))) const unsigned int glb_u32;
typedef __attribute__((address_space(3))) unsigned int       lds_u32;

__device__ __forceinline__ short f2bf(float v) {
    __hip_bfloat16 b = __float2bfloat16(v);      // RNE; pairs fuse to v_cvt_pk_bf16_f32
    return __builtin_bit_cast(short, b);
}
__device__ __forceinline__ float bf2f(unsigned short b) {
    return __uint_as_float(((unsigned)b) << 16);
}

// ---------------- zero scratch (replaces pathological hipMemsetAsync fill) ----
__global__ __launch_bounds__(256) void zero_k(int4* __restrict__ p, int n4) {
    int i = blockIdx.x * 256 + threadIdx.x;
    if (i < n4) p[i] = make_int4(0, 0, 0, 0);
}

// ---------------- degree count (int) ----------------
__global__ __launch_bounds__(256) void count_k(const int* __restrict__ dst,
                                               int* __restrict__ cnt) {
    int e = blockIdx.x * 256 + threadIdx.x;
    if (e < EE) atomicAdd(&cnt[dst[e]], 1);
}

// ---------------- hierarchical exclusive scan of cnt -> rowptr ----------------
__global__ __launch_bounds__(256) void scan1_k(const int* __restrict__ cnt,
                                               int* __restrict__ rowptr,
                                               int* __restrict__ bsum) {
    __shared__ int s[256];
    int t = threadIdx.x;
    int i = blockIdx.x * 256 + t;
    int v = (i < NN) ? cnt[i] : 0;
    s[t] = v; __syncthreads();
    for (int off = 1; off < 256; off <<= 1) {
        int x = (t >= off) ? s[t - off] : 0;
        __syncthreads();
        s[t] += x;
        __syncthreads();
    }
    if (i < NN) rowptr[i] = s[t] - v;           // block-local exclusive
    if (t == 255) bsum[blockIdx.x] = s[255];
}

__global__ __launch_bounds__(1024) void scan2_k(int* __restrict__ bsum) {
    __shared__ int s[1024];
    int t = threadIdx.x;
    int v = (t < NBLK) ? bsum[t] : 0;
    s[t] = v; __syncthreads();
    for (int off = 1; off < 1024; off <<= 1) {
        int x = (t >= off) ? s[t - off] : 0;
        __syncthreads();
        s[t] += x;
        __syncthreads();
    }
    if (t < NBLK) bsum[t] = s[t] - v;           // exclusive block offsets
}

// scan3 + dis fused
__global__ __launch_bounds__(256) void scan3_k(int* __restrict__ rowptr,
                                               const int* __restrict__ bsum,
                                               int* __restrict__ cur,
                                               const int* __restrict__ cnt,
                                               float* __restrict__ dis) {
    int i = blockIdx.x * 256 + threadIdx.x;
    if (i < NN) {
        int v = rowptr[i] + bsum[blockIdx.x];
        rowptr[i] = v;
        cur[i] = v;
        dis[i] = rsqrtf((float)cnt[i] + 1.0f);
    }
    if (i == 0) rowptr[NN] = EE;
}

// ---------------- CSR fill (counting sort by dst), packed (src, dis[src]) ----
__global__ __launch_bounds__(256) void fill_k(const int* __restrict__ src,
                                              const int* __restrict__ dst,
                                              const float* __restrict__ dis,
                                              int* __restrict__ cur,
                                              int2* __restrict__ sedge) {
    int e = blockIdx.x * 256 + threadIdx.x;
    if (e < EE) {
        int d = dst[e], s = src[e];
        int pos = atomicAdd(&cur[d], 1);
        sedge[pos] = make_int2(s, __float_as_int(dis[s]));
    }
}

// ---------------- Wfrag prep: per-lane MFMA fragments, bf16 ----------------
// F[((ct*4 + kk)*64 + lane)*8 + e] = W[kk*32 + (lane>>4)*8 + e][ct*16 + (lane&15)]
// Serves as the MFMA A-operand in the swapped scheme.
__global__ __launch_bounds__(256) void wfrag_k(const float* __restrict__ W1,
                                               const float* __restrict__ W2,
                                               short* __restrict__ F1,
                                               short* __restrict__ F2) {
    int idx = blockIdx.x * 256 + threadIdx.x;   // [0, 32768)
    int m = idx >> 14;
    int i = idx & 16383;
    int e  = i & 7;
    int l  = (i >> 3) & 63;
    int kk = (i >> 9) & 3;
    int ct = i >> 11;
    int k = kk * 32 + (l >> 4) * 8 + e;
    int c = ct * 16 + (l & 15);
    const float* W = m ? W2 : W1;
    short*       F = m ? F2 : F1;
    F[i] = f2bf(W[k * DD + c]);
}

// ---------------- MFMA GEMM, LDS-staged via global_load_lds ----------------
// MODE 0: A = concat(A0[0:nsplit], A1) fp32, raw.            Layer 1.
// MODE 1: A = relu(bf16(Ab) * coefs[c] + coefs[128+c]).      Layer 2.
// One 64-row tile per block, staged with width-16 global_load_lds (padded
// row stride vs bank conflicts). Epilogue: acc -> LDS (272B padded stride)
// -> fully coalesced 16B/lane row stores.
template<int MODE>
__global__ __launch_bounds__(256) void gemm_mfma_k(const float* __restrict__ A0,
                                                   const float* __restrict__ A1,
                                                   int nsplit,
                                                   const unsigned short* __restrict__ Ab,
                                                   const float* __restrict__ coefs,
                                                   const short* __restrict__ Wfrag,
                                                   unsigned short* __restrict__ hout) {
    constexpr int ROWB  = (MODE == 0) ? 528 : 272;   // padded LDS row stride (bytes)
    constexpr int PAY   = (MODE == 0) ? 512 : 256;   // payload bytes per row
    constexpr int TILEB = 64 * ROWB;
    constexpr int NCH   = TILEB / 16;                // 16B chunks (2112 / 1088)
    constexpr int FULLR = NCH / 256;                 // full staging rounds (8 / 4)

    __shared__ __align__(16) char smem[TILEB];       // >= 64*272 epilogue bytes

    int t    = threadIdx.x;
    int wave = t >> 6;
    int lane = t & 63;
    int kgrp = lane >> 4;        // 0..3
    int lrow = lane & 15;
    int r0   = blockIdx.x * 64;

    // ---- stage tile into LDS ----
#pragma unroll
    for (int r = 0; r < FULLR; ++r) {
        int chunk = r * 256 + t;
        int o     = chunk * 16;
        int row   = o / ROWB;
        int inner = o - row * ROWB;
        if (inner >= PAY) inner = 0;                 // padding chunk: safe in-row read
        int gr = r0 + row; if (gr > NN - 1) gr = NN - 1;
        const char* src;
        if (MODE == 0) src = (const char*)((gr < nsplit) ? (A0 + (size_t)gr * DD)
                                                         : (A1 + (size_t)(gr - nsplit) * DD)) + inner;
        else           src = (const char*)(Ab + (size_t)gr * DD) + inner;
        lds_u32* dst = (lds_u32*)(smem + r * 4096 + wave * 1024);  // wave-uniform base
        __builtin_amdgcn_global_load_lds((glb_u32*)src, dst, 16, 0, 0);
    }
    if (wave == 0) {                                 // remaining 64 chunks
        int chunk = FULLR * 256 + lane;
        int o     = chunk * 16;
        int row   = o / ROWB;
        int inner = o - row * ROWB;
        if (inner >= PAY) inner = 0;
        int gr = r0 + row; if (gr > NN - 1) gr = NN - 1;
        const char* src;
        if (MODE == 0) src = (const char*)((gr < nsplit) ? (A0 + (size_t)gr * DD)
                                                         : (A1 + (size_t)(gr - nsplit) * DD)) + inner;
        else           src = (const char*)(Ab + (size_t)gr * DD) + inner;
        lds_u32* dst = (lds_u32*)(smem + FULLR * 4096);
        __builtin_amdgcn_global_load_lds((glb_u32*)src, dst, 16, 0, 0);
    }
    __syncthreads();   // drains vmcnt(0): staged tile visible

    // ---- compute: 16 rows/wave, all 128 cols ----
    const char* arow = smem + (wave * 16 + lrow) * ROWB;

    f32x4 acc[8];
#pragma unroll
    for (int ct = 0; ct < 8; ++ct) acc[ct] = (f32x4){0.f, 0.f, 0.f, 0.f};

    const short8* wf = (const short8*)Wfrag;

#pragma unroll
    for (int kk = 0; kk < 4; ++kk) {
        short8 rfrag;
        if (MODE == 0) {
            f32x4 va = *(const f32x4*)(arow + kk * 128 + kgrp * 32);
            f32x4 vb = *(const f32x4*)(arow + kk * 128 + kgrp * 32 + 16);
#pragma unroll
            for (int j = 0; j < 4; ++j) { rfrag[j] = f2bf(va[j]); rfrag[4 + j] = f2bf(vb[j]); }
        } else {
            int d0 = kk * 32 + kgrp * 8;
            ushort8 u = *(const ushort8*)(arow + kk * 64 + kgrp * 16);
            f32x4 s1 = *(const f32x4*)(coefs + d0);
            f32x4 s2 = *(const f32x4*)(coefs + d0 + 4);
            f32x4 t1 = *(const f32x4*)(coefs + 128 + d0);
            f32x4 t2 = *(const f32x4*)(coefs + 128 + d0 + 4);
#pragma unroll
            for (int j = 0; j < 4; ++j) {
                rfrag[j]     = f2bf(fmaxf(bf2f(u[j])     * s1[j] + t1[j], 0.f));
                rfrag[4 + j] = f2bf(fmaxf(bf2f(u[4 + j]) * s2[j] + t2[j], 0.f));
            }
        }
#pragma unroll
        for (int ct = 0; ct < 8; ++ct) {
            short8 wfr = wf[(ct * 4 + kk) * 64 + lane];
            acc[ct] = __builtin_amdgcn_mfma_f32_16x16x32_bf16(wfr, rfrag, acc[ct], 0, 0, 0);
        }
    }

    // ---- epilogue: acc -> LDS (272B stride) -> coalesced 16B/lane stores ----
    __syncthreads();   // all LDS tile reads done; safe to overwrite
    {
        char* od = smem + (wave * 16 + lrow) * 272 + kgrp * 8;
#pragma unroll
        for (int ct = 0; ct < 8; ++ct) {
            unsigned p0 = (unsigned)(unsigned short)f2bf(acc[ct][0])
                        | ((unsigned)(unsigned short)f2bf(acc[ct][1]) << 16);
            unsigned p1 = (unsigned)(unsigned short)f2bf(acc[ct][2])
                        | ((unsigned)(unsigned short)f2bf(acc[ct][3]) << 16);
            uint2 p; p.x = p0; p.y = p1;
            *(uint2*)(od + ct * 32) = p;             // col bytes = ct*32 + kgrp*8
        }
    }
    __syncthreads();
#pragma unroll
    for (int c = 0; c < 4; ++c) {
        int chunk = c * 256 + t;                     // 1024 chunks of 16B
        int row   = chunk >> 4;
        int inner = (chunk & 15) * 16;
        int gr = r0 + row;
        if (gr < NN) {
            uint4 v = *(const uint4*)(smem + row * 272 + inner);
            *(uint4*)((char*)hout + (size_t)gr * 256 + inner) = v;
        }
    }
}

// ---------------- CSR gather: 4 rows per wave (16-lane groups, ushort8) -----
// aggb[i] = bf16( dis[i]*sum(dis[s]*h[s]) + dis[i]^2*h[i] )
__global__ __launch_bounds__(256) void gather_k(const unsigned short* __restrict__ h,
                                                const int2* __restrict__ se,
                                                const int* __restrict__ rowptr,
                                                const float* __restrict__ dis,
                                                unsigned short* __restrict__ aggb) {
    int t = threadIdx.x;
    int l = t & 15;                       // lane within row-group (8 cols each)
    int row = blockIdx.x * 16 + (t >> 4); // 16 rows per block (4 per wave)
    if (row >= NN) return;
    int p0 = rowptr[row], p1 = rowptr[row + 1];
    const ushort8* hp = (const ushort8*)h;

    float acc[8];
#pragma unroll
    for (int j = 0; j < 8; ++j) acc[j] = 0.f;

    for (int base = p0; base < p1; base += 4) {
        int i1 = min(base + 1, p1 - 1);
        int i2 = min(base + 2, p1 - 1);
        int i3 = min(base + 3, p1 - 1);
        int2 e0 = se[base], e1 = se[i1], e2 = se[i2], e3 = se[i3];
        ushort8 h0 = hp[(size_t)e0.x * 16 + l];
        ushort8 h1 = hp[(size_t)e1.x * 16 + l];
        ushort8 h2 = hp[(size_t)e2.x * 16 + l];
        ushort8 h3 = hp[(size_t)e3.x * 16 + l];
        float w0 = __int_as_float(e0.y);
        float w1 = (base + 1 < p1) ? __int_as_float(e1.y) : 0.f;
        float w2 = (base + 2 < p1) ? __int_as_float(e2.y) : 0.f;
        float w3 = (base + 3 < p1) ? __int_as_float(e3.y) : 0.f;
#pragma unroll
        for (int j = 0; j < 8; ++j) {
            acc[j] += w0 * bf2f(h0[j]) + w1 * bf2f(h1[j])
                    + w2 * bf2f(h2[j]) + w3 * bf2f(h3[j]);
        }
    }
    float d  = dis[row];
    float d2 = d * d;
    ushort8 hs = hp[(size_t)row * 16 + l];
    ushort8 o;
#pragma unroll
    for (int j = 0; j < 8; ++j)
        o[j] = (unsigned short)f2bf(d * acc[j] + d2 * bf2f(hs[j]));
    ((ushort8*)aggb)[(size_t)row * 16 + l] = o;
}

// ---------------- BN stats on bf16 x: per-column sum & sumsq ----------------
__global__ __launch_bounds__(256) void bnstats_k(const unsigned short* __restrict__ x,
                                                 float* __restrict__ sums) {
    int t  = threadIdx.x;
    int co = (t & 15) * 8;     // column octet
    int rg = t >> 4;           // 0..15
    float s[8], s2[8];
#pragma unroll
    for (int j = 0; j < 8; ++j) { s[j] = 0.f; s2[j] = 0.f; }
    for (int r = blockIdx.x * 16 + rg; r < NN; r += gridDim.x * 16) {
        ushort8 v = *(const ushort8*)(x + (size_t)r * DD + co);
#pragma unroll
        for (int j = 0; j < 8; ++j) {
            float f = bf2f(v[j]);
            s[j] += f; s2[j] += f * f;
        }
    }
    __shared__ float red[16][128];
#pragma unroll
    for (int j = 0; j < 8; ++j) red[rg][co + j] = s[j];
    __syncthreads();
    if (t < 128) {
        float a = 0.f;
#pragma unroll
        for (int g = 0; g < 16; ++g) a += red[g][t];
        atomicAdd(&sums[t], a);
    }
    __syncthreads();
#pragma unroll
    for (int j = 0; j < 8; ++j) red[rg][co + j] = s2[j];
    __syncthreads();
    if (t < 128) {
        float a = 0.f;
#pragma unroll
        for (int g = 0; g < 16; ++g) a += red[g][t];
        atomicAdd(&sums[128 + t], a);
    }
}

// ---------------- BN coefficients ----------------
__global__ void bncoef_k(const float* __restrict__ sums,
                         const float* __restrict__ gamma,
                         const float* __restrict__ beta,
                         float* __restrict__ coefs) {
    int c = threadIdx.x;
    if (c >= DD) return;
    const float n = (float)NN;
    float m  = sums[c] / n;
    float v  = sums[128 + c] / n - m * m;
    float is = rsqrtf(v + 1e-5f);
    float sc = gamma[c] * is;
    coefs[c] = sc;
    coefs[128 + c] = beta[c] - m * sc;
}

// ---------------- ratings: wave per pair, BN2+relu inline (bf16 x) ----------
__global__ __launch_bounds__(256) void ratings_k(const unsigned short* __restrict__ x,
                                                 const int* __restrict__ srcn,
                                                 const int* __restrict__ dstn,
                                                 const float* __restrict__ coefs,
                                                 float* __restrict__ out) {
    int wid  = (blockIdx.x * 256 + threadIdx.x) >> 6;
    int lane = threadIdx.x & 63;
    if (wid >= BB) return;
    int u = srcn[wid], v = dstn[wid];
    const ushort2* xp = (const ushort2*)x;
    ushort2 a = xp[(size_t)u * 64 + lane];
    ushort2 b = xp[(size_t)v * 64 + lane];
    float2 sc = ((const float2*)coefs)[lane];
    float2 sh = ((const float2*)(coefs + 128))[lane];
    float ax = fmaxf(bf2f(a.x) * sc.x + sh.x, 0.f);
    float ay = fmaxf(bf2f(a.y) * sc.y + sh.y, 0.f);
    float bx = fmaxf(bf2f(b.x) * sc.x + sh.x, 0.f);
    float by = fmaxf(bf2f(b.y) * sc.y + sh.y, 0.f);
    float acc = ax * bx + ay * by;
#pragma unroll
    for (int off = 32; off; off >>= 1) acc += __shfl_down(acc, off, 64);
    if (lane == 0) out[wid] = acc;
}

extern "C" void kernel_launch(void* const* d_in, const int* in_sizes, int n_in,
                              void* d_out, int out_size, void* d_ws, size_t ws_size,
                              hipStream_t stream) {
    const int*   edge  = (const int*)d_in[0];      // [2,E]
    const int*   esrc  = edge;
    const int*   edst  = edge + EE;
    const int*   srcn  = (const int*)d_in[2];
    const int*   dstn  = (const int*)d_in[3];
    const float* uemb  = (const float*)d_in[4];
    const float* bemb  = (const float*)d_in[5];
    const float* W1    = (const float*)d_in[6];
    // b1 = d_in[7]  (per-column constant, cancels in BN)
    const float* g1    = (const float*)d_in[8];
    const float* be1   = (const float*)d_in[9];
    const float* W2    = (const float*)d_in[10];
    // b2 = d_in[11] (cancels in BN)
    const float* g2    = (const float*)d_in[12];
    const float* be2   = (const float*)d_in[13];
    float* out = (float*)d_out;

    // workspace layout (16B-aligned segments; NN padded to 150016)
    unsigned short* aggb   = (unsigned short*)d_ws;                      // N*D bf16
    unsigned short* hbuf   = aggb + (size_t)NN * DD;                     // N*D bf16
    int*            cnt    = (int*)(hbuf + (size_t)NN * DD);             // 150016
    float*          sums1  = (float*)(cnt + 150016);                     // 256 (zeroed with cnt)
    float*          sums2  = sums1 + 256;                                // 256 (zeroed with cnt)
    int*            rowptr = (int*)(sums2 + 256);                        // 150016 (>= NN+1)
    int*            cur    = rowptr + 150016;                            // 150016
    float*          dis    = (float*)(cur + 150016);                     // 150016
    int2*           sedge  = (int2*)(dis + 150016);                      // EE int2 (scan scratch first)
    short*          Wf1    = (short*)(sedge + EE);                       // 16384 bf16
    short*          Wf2    = Wf1 + 16384;                                // 16384 bf16
    float*          coef1  = (float*)(Wf2 + 16384);                      // 256
    float*          coef2  = coef1 + 256;                                // 256

    const int egrid = (EE + 255) / 256;            // 1954
    const int ggrid = (NN + 63) / 64;              // 2344 MFMA-GEMM blocks (64 rows each)
    const int agrid = (NN + 15) / 16;              // 9375 gather blocks (4 rows/wave)
    int* bsum = (int*)sedge;                       // scan scratch (sedge unwritten until fill_k)

    // ---- CSR build + normalization + W fragments ----
    zero_k<<<147, 256, 0, stream>>>((int4*)cnt, (150016 + 512) / 4);     // cnt + sums1 + sums2
    count_k<<<egrid, 256, 0, stream>>>(edst, cnt);
    scan1_k<<<NBLK, 256, 0, stream>>>(cnt, rowptr, bsum);
    scan2_k<<<1, 1024, 0, stream>>>(bsum);
    scan3_k<<<NBLK, 256, 0, stream>>>(rowptr, bsum, cur, cnt, dis);
    fill_k<<<egrid, 256, 0, stream>>>(esrc, edst, dis, cur, sedge);
    wfrag_k<<<128, 256, 0, stream>>>(W1, W2, Wf1, Wf2);

    // ---- layer 1 ----
    gemm_mfma_k<0><<<ggrid, 256, 0, stream>>>(uemb, bemb, NUSERS, nullptr, nullptr, Wf1, hbuf);
    gather_k<<<agrid, 256, 0, stream>>>(hbuf, sedge, rowptr, dis, aggb);
    bnstats_k<<<512, 256, 0, stream>>>(aggb, sums1);
    bncoef_k<<<1, 128, 0, stream>>>(sums1, g1, be1, coef1);

    // ---- layer 2 (BN1+relu fused into GEMM A-load, bf16 A) ----
    gemm_mfma_k<1><<<ggrid, 256, 0, stream>>>(nullptr, nullptr, 0, aggb, coef1, Wf2, hbuf);
    gather_k<<<agrid, 256, 0, stream>>>(hbuf, sedge, rowptr, dis, aggb);
    bnstats_k<<<512, 256, 0, stream>>>(aggb, sums2);
    bncoef_k<<<1, 128, 0, stream>>>(sums2, g2, be2, coef2);

    // ---- ratings (BN2+relu inline) ----
    ratings_k<<<BB / 4, 256, 0, stream>>>(aggb, srcn, dstn, coef2, out);
}